// Round 5
// baseline (282.297 us; speedup 1.0000x reference)
//
#include <hip/hip_runtime.h>
#include <math.h>

#define B_ 2
#define N_ 16384
#define V_ 10475
#define J_ 55
#define K_ 6

constexpr int VPAD = 12288;          // 6 * 2048 (padded with far sentinels)
constexpr int TILE = 2048;           // verts per LDS tile
constexpr int WAVES = 16;            // points per block (one per wave)
constexpr int KBLK = WAVES * 64;     // 1024 threads

// ---------------------------------------------------------------------------
// P0: pack verts as (x,y,z,v2) into padded ws buffer; pad region = far
// sentinels (always lose to real verts; decoded idx >= V_ guarded anyway).
// ---------------------------------------------------------------------------
__global__ __launch_bounds__(256) void prep_kernel(const float* __restrict__ pverts,
                                                   float4* __restrict__ pv) {
    int i = blockIdx.x * 256 + threadIdx.x;
    if (i >= B_ * VPAD) return;
    int b = i / VPAD;
    int vi = i - b * VPAD;
    if (vi < V_) {
        const float* vp = pverts + ((size_t)(b * V_ + vi)) * 3;
        float vx = vp[0], vy = vp[1], vz = vp[2];
        pv[i] = make_float4(vx, vy, vz, vx * vx + vy * vy + vz * vz);
    } else {
        pv[i] = make_float4(0.f, 0.f, 0.f, 3.0e38f);
    }
}

__device__ __forceinline__ double shfl_d(double v, int src) {
    int lo = __double2loint(v), hi = __double2hiint(v);
    lo = __shfl(lo, src, 64);
    hi = __shfl(hi, src, 64);
    return __hiloint2double(hi, lo);
}

// ---------------------------------------------------------------------------
// K1 (fused): wave-per-point KNN screen with shared gate + bitonic cross-lane
// merge (top-8 by key) + f64 re-rank (reference arithmetic, stable ties) +
// conf/weight/blend/apply epilogue. Everything for a point in one wave.
//
// Key = (d2+bias)[31:14] | vert_idx[13:0]; gate = min over lanes of each
// lane's 6th-best key — conservative vs the true global 6th (proof: any
// final-top-6 key has <=5 smaller keys ever, so every 6th-of-seen > it).
// ---------------------------------------------------------------------------
__global__ __launch_bounds__(KBLK, 8) void knn_kernel(const float4* __restrict__ pv,
                                                      const float* __restrict__ x,
                                                      const float* __restrict__ cam,
                                                      const float* __restrict__ lbs,
                                                      const float* __restrict__ vt,
                                                      float* __restrict__ out) {
    __shared__ float4 tile[TILE];

    const int tid = threadIdx.x, lane = tid & 63, wid = tid >> 6;
    const int b = blockIdx.x >> 10;                 // 1024 blocks per batch
    const int n = ((blockIdx.x & 1023) << 4) | wid; // 16 points per block
    const int gp = b * N_ + n;

    const float cs = cam[b * 3 + 0], ctx = cam[b * 3 + 1], cty = cam[b * 3 + 2];
    const float Px = x[gp * 3 + 0] / cs - ctx;
    const float Py = x[gp * 3 + 1] / cs - cty;
    const float Pz = x[gp * 3 + 2] / cs;
    // bias 1e-4 > worst f32 cancellation (~2e-5) keeps d2 > 0 so uint-bit
    // compare == float compare; constant shift preserves order.
    const float Ax = -2.f * Px, Ay = -2.f * Py, Az = -2.f * Pz;
    const float Cc = Px * Px + Py * Py + Pz * Pz + 1.0e-4f;

    unsigned int bK[6];
#pragma unroll
    for (int t = 0; t < 6; ++t) bK[t] = 0xFFFFFFFFu;
    unsigned int gate = 0xFFFFFFFFu;

    const float4* vb = pv + b * VPAD;
    for (int t0 = 0; t0 < VPAD; t0 += TILE) {
        tile[tid]        = vb[t0 + tid];
        tile[tid + 1024] = vb[t0 + tid + 1024];
        __syncthreads();
#pragma unroll 1
        for (int half = 0; half < 2; ++half) {
            const int hb = half << 10;
#pragma unroll 4
            for (int jj = 0; jj < 16; ++jj) {
                const int j = hb + (jj << 6) + lane;
                float4 q = tile[j];
                float d2 = fmaf(Ax, q.x, fmaf(Ay, q.y, fmaf(Az, q.z, Cc + q.w)));
                unsigned int key = (__float_as_uint(d2) & 0xFFFFC000u)
                                 | (unsigned int)(t0 + j);     // VPAD < 2^14
                bool hit = key < gate;
                if (__any(hit)) {                 // shared insert event
                    unsigned int kk = hit ? key : 0xFFFFFFFFu; // no-op insert
#pragma unroll
                    for (int t = 0; t < 6; ++t) {
                        unsigned int mn = min(kk, bK[t]);
                        kk = max(kk, bK[t]);
                        bK[t] = mn;
                    }
                }
            }
            // refresh shared gate: min over lanes of lane-local 6th best
            unsigned int g = bK[5];
#pragma unroll
            for (int m = 1; m <= 32; m <<= 1)
                g = min(g, (unsigned int)__shfl_xor((int)g, m, 64));
            gate = g;
        }
        __syncthreads();
    }

    // ---- cross-lane bitonic merge: global top-8 by key, all lanes ----
    unsigned int E[8];
#pragma unroll
    for (int t = 0; t < 6; ++t) E[t] = bK[t];
    E[6] = 0xFFFFFFFFu; E[7] = 0xFFFFFFFFu;
#pragma unroll
    for (int s = 1; s <= 32; s <<= 1) {
        unsigned int Bt[8], Cv[8];
#pragma unroll
        for (int t = 0; t < 8; ++t) Bt[t] = (unsigned int)__shfl_xor((int)E[t], s, 64);
#pragma unroll
        for (int t = 0; t < 8; ++t) Cv[t] = min(E[t], Bt[7 - t]); // keep-8, bitonic
#define CE_(a, c) { unsigned int mn_ = min(Cv[a], Cv[c]); Cv[c] = max(Cv[a], Cv[c]); Cv[a] = mn_; }
        CE_(0, 4) CE_(1, 5) CE_(2, 6) CE_(3, 7)
        CE_(0, 2) CE_(1, 3) CE_(4, 6) CE_(5, 7)
        CE_(0, 1) CE_(2, 3) CE_(4, 5) CE_(6, 7)
#undef CE_
#pragma unroll
        for (int t = 0; t < 8; ++t) E[t] = Cv[t];
    }

    // ---- f64 re-rank of the 8-candidate superset (reference formula) ----
    double myd = 1.0e300;
    int mygi = 0x7FFFFFFF;
    if (lane < 8) {
        mygi = (int)(E[lane] & 0x3FFFu);
        if (mygi < V_) {
            const double csd = (double)cs;
            const double PX = (double)x[gp * 3 + 0] / csd - (double)ctx;
            const double PY = (double)x[gp * 3 + 1] / csd - (double)cty;
            const double PZ = (double)x[gp * 3 + 2] / csd;
            float4 vq = vb[mygi];
            double vx = (double)vq.x, vy = (double)vq.y, vz = (double)vq.z;
            double v2 = vx * vx + vy * vy + vz * vz;
            double P2 = PX * PX + PY * PY + PZ * PZ;
            double dot = PX * vx + PY * vy + PZ * vz;
            myd = P2 + v2 - 2.0 * dot;            // reference expanded form
        }
    }
    // broadcast 8 (d, idx) pairs to all lanes
    double dd[8];
    int ii[8];
#pragma unroll
    for (int t = 0; t < 8; ++t) { dd[t] = shfl_d(myd, t); ii[t] = __shfl(mygi, t, 64); }
    // odd-even transposition sort-8, stable by (d, idx) — static indexing,
    // computed redundantly on all lanes (identical data, no divergence)
#define CE_(a, c) { \
        bool sw_ = (dd[a] > dd[c]) || (dd[a] == dd[c] && ii[a] > ii[c]); \
        double dt_ = sw_ ? dd[a] : dd[c]; dd[a] = sw_ ? dd[c] : dd[a]; dd[c] = dt_; \
        int it_ = sw_ ? ii[a] : ii[c]; ii[a] = sw_ ? ii[c] : ii[a]; ii[c] = it_; }
#pragma unroll
    for (int r = 0; r < 4; ++r) {
        CE_(0, 1) CE_(2, 3) CE_(4, 5) CE_(6, 7)
        CE_(1, 2) CE_(3, 4) CE_(5, 6)
    }
#undef CE_

    // ---- fused epilogue (f32: all decisions have >>1e3 margin) ----
    const int i0 = ii[0];
    float r0v = (lane < J_) ? lbs[i0 * J_ + lane] : 0.f;
    float wgt[K_];
    wgt[0] = expf(-fmaxf((float)dd[0], 0.f));     // conf(k=0) == 1 always
#pragma unroll
    for (int k = 1; k < K_; ++k) {
        float rkv = (lane < J_) ? lbs[ii[k] * J_ + lane] : 0.f;
        float sv = fabsf(rkv - r0v);
#pragma unroll
        for (int m = 1; m <= 32; m <<= 1) sv += __shfl_xor(sv, m, 64);
        // conf > 0.9  <=>  ssum < -WSTD2*ln(0.9) = 0.0021072103
        wgt[k] = (sv < 0.0021072103f) ? expf(-fmaxf((float)dd[k], 0.f)) : 0.f;
    }
    float wsum = ((wgt[0] + wgt[1]) + (wgt[2] + wgt[3])) + (wgt[4] + wgt[5]);
    float inv = 1.f / wsum;

    float acc = 0.f;
    if (lane < 16) {                               // lane = 4x4 element (r,c)
#pragma unroll
        for (int k = 0; k < K_; ++k)
            acc += (wgt[k] * inv) * vt[((size_t)(b * V_ + ii[k])) * 16 + lane];
    }
    const int c = lane & 3;
    float pc = (c == 0) ? Px : (c == 1) ? Py : (c == 2) ? Pz : 1.f;
    float part = acc * pc;
    part += __shfl_xor(part, 1, 64);
    part += __shfl_xor(part, 2, 64);
    if (lane == 0)      out[gp * 3 + 0] = part;
    else if (lane == 4) out[gp * 3 + 1] = part;
    else if (lane == 8) out[gp * 3 + 2] = part;
}

// ---------------------------------------------------------------------------
extern "C" void kernel_launch(void* const* d_in, const int* in_sizes, int n_in,
                              void* d_out, int out_size, void* d_ws, size_t ws_size,
                              hipStream_t stream) {
    const float* x      = (const float*)d_in[0];  // [B,N,3]
    const float* cam    = (const float*)d_in[1];  // [B,3]
    const float* lbs    = (const float*)d_in[2];  // [V,J]
    const float* vt     = (const float*)d_in[3];  // [B,V,4,4]
    const float* pverts = (const float*)d_in[4];  // [B,V,3]
    float* out = (float*)d_out;                   // [B,N,3]

    float4* pv = (float4*)d_ws;                   // B*VPAD float4 (393 KB)

    prep_kernel<<<(B_ * VPAD + 255) / 256, 256, 0, stream>>>(pverts, pv);
    knn_kernel<<<B_ * (N_ / WAVES), KBLK, 0, stream>>>(pv, x, cam, lbs, vt, out);
}